// Round 1
// baseline (430.806 us; speedup 1.0000x reference)
//
#include <hip/hip_runtime.h>
#include <stdint.h>

// ---------- types ----------
typedef float f32x4 __attribute__((ext_vector_type(4)));
typedef __bf16 bf16x8 __attribute__((ext_vector_type(8)));
typedef __bf16 bf16x8_a __attribute__((ext_vector_type(8), may_alias));
typedef unsigned int u32x4_a __attribute__((ext_vector_type(4), may_alias));
typedef unsigned short u16x4_a __attribute__((ext_vector_type(4), may_alias));

#define DEV __device__ __forceinline__

DEV unsigned short f2b(float f) {  // f32 -> bf16 RNE
  unsigned int u = __float_as_uint(f);
  u = u + 0x7FFFu + ((u >> 16) & 1u);
  return (unsigned short)(u >> 16);
}

// async global->LDS, 16B per lane; LDS dest is wave-uniform base + lane*16
#define GLOAD_LDS16(gsrc, ldst)                                                  \
  __builtin_amdgcn_global_load_lds(                                              \
      (__attribute__((address_space(1))) void*)(uintptr_t)(const void*)(gsrc),   \
      (__attribute__((address_space(3))) void*)(ldst), 16, 0, 0)

// ---------- conversion kernels ----------
__global__ __launch_bounds__(256) void cvt_kernel(const float* __restrict__ in,
                                                  unsigned short* __restrict__ out, int n4) {
  int i = blockIdx.x * 256 + threadIdx.x;
  if (i < n4) {
    float4 v = ((const float4*)in)[i];
    u16x4_a t = {f2b(v.x), f2b(v.y), f2b(v.z), f2b(v.w)};
    ((u16x4_a*)out)[i] = t;
  }
}

// in: [rows][cols] f32 (batched on z) -> out: [cols][rows] bf16 (*scale)
__global__ __launch_bounds__(256) void transpose_cvt(const float* __restrict__ in,
                                                     unsigned short* __restrict__ out,
                                                     int rows, int cols, float scale) {
  __shared__ float tile[32][33];
  const int tx = threadIdx.x & 31, ty = threadIdx.x >> 5;
  const int c0 = blockIdx.x * 32, r0 = blockIdx.y * 32;
  const float* ip = in + (size_t)blockIdx.z * rows * cols;
  unsigned short* op = out + (size_t)blockIdx.z * rows * cols;
#pragma unroll
  for (int j = 0; j < 32; j += 8)
    tile[ty + j][tx] = ip[(size_t)(r0 + ty + j) * cols + (c0 + tx)];
  __syncthreads();
#pragma unroll
  for (int j = 0; j < 32; j += 8)
    op[(size_t)(c0 + ty + j) * rows + (r0 + tx)] = f2b(tile[tx][ty + j] * scale);
}

__global__ void build_bias_qkv(const float* __restrict__ bq, const float* __restrict__ bk,
                               const float* __restrict__ bv, float* __restrict__ out) {
  int c = blockIdx.x * 256 + threadIdx.x;  // 0..3071
  int which = c >> 10, idx = c & 1023;
  float v = which == 0 ? bq[idx] : (which == 1 ? bk[idx] : bv[idx]);
  out[c] = which == 0 ? v * 0.125f : v;  // fold 1/sqrt(HD) into q
}

// ---------- GEMM: C[M][N] = A[M][K](bf16) * Bt[N][K]^T(bf16), m97 structure ----------
// EP 0: QKV scatter->bf16 [B,H,S,HD] (+bias). EP 1: f32 out = acc+bias+addf (residual).
// EP 2: bf16 out = relu(acc+bias).
template <int EP>
__global__ __launch_bounds__(256) void gemm_bt_kernel(
    const unsigned short* __restrict__ A, const unsigned short* __restrict__ Bt,
    int M, int N, int K,
    const float* __restrict__ bias, const float* __restrict__ addf,
    float* __restrict__ outf, unsigned short* __restrict__ outb,
    unsigned short* __restrict__ q_out, unsigned short* __restrict__ k_out,
    unsigned short* __restrict__ v_out) {
  __shared__ __align__(16) unsigned short sA[128 * 32];
  __shared__ __align__(16) unsigned short sB[128 * 32];
  const int tid = threadIdx.x;
  const int wid = tid >> 6, lane = tid & 63;
  const int g = lane >> 4, r15 = lane & 15;
  const int wr = wid >> 1, wc = wid & 1;
  const int row0 = blockIdx.y * 128, col0 = blockIdx.x * 128;

  f32x4 acc[4][4] = {};

  const int c0 = wid * 128 + lane;
  const unsigned short* gA0 = A + (size_t)row0 * K;
  const unsigned short* gB0 = Bt + (size_t)col0 * K;

  for (int k0 = 0; k0 < K; k0 += 32) {
#pragma unroll
    for (int j = 0; j < 2; ++j) {
      int c = c0 + j * 64;
      GLOAD_LDS16(gA0 + (size_t)(c >> 2) * K + k0 + (c & 3) * 8, &sA[(wid * 128 + j * 64) * 8]);
      GLOAD_LDS16(gB0 + (size_t)(c >> 2) * K + k0 + (c & 3) * 8, &sB[(wid * 128 + j * 64) * 8]);
    }
    __syncthreads();
    bf16x8 af[4], bfr[4];
#pragma unroll
    for (int m = 0; m < 4; ++m)
      af[m] = *(const bf16x8_a*)&sA[(wr * 64 + m * 16 + r15) * 32 + g * 8];
#pragma unroll
    for (int n = 0; n < 4; ++n)
      bfr[n] = *(const bf16x8_a*)&sB[(wc * 64 + n * 16 + r15) * 32 + g * 8];
#pragma unroll
    for (int m = 0; m < 4; ++m)
#pragma unroll
      for (int n = 0; n < 4; ++n)
        acc[m][n] = __builtin_amdgcn_mfma_f32_16x16x32_bf16(af[m], bfr[n], acc[m][n], 0, 0, 0);
    __syncthreads();
  }

// epilogue: D row = row0+wr*64+m*16+g*4+r ; col = col0+wc*64+n*16+r15
#pragma unroll
  for (int m = 0; m < 4; ++m) {
    const int rbase = row0 + wr * 64 + m * 16 + g * 4;
#pragma unroll
    for (int n = 0; n < 4; ++n) {
      const int col = col0 + wc * 64 + n * 16 + r15;
      const float bb = bias[col];
#pragma unroll
      for (int r = 0; r < 4; ++r) {
        const int row = rbase + r;
        float v = acc[m][n][r] + bb;
        if constexpr (EP == 0) {
          int which = col >> 10, cc = col & 1023;
          int h = cc >> 6, e = cc & 63;
          int b = row >> 11, s = row & 2047;
          unsigned short* dst = which == 0 ? q_out : (which == 1 ? k_out : v_out);
          dst[(((size_t)(b * 16 + h) * 2048) + s) * 64 + e] = f2b(v);
        } else if constexpr (EP == 1) {
          size_t idx = (size_t)row * N + col;
          outf[idx] = v + addf[idx];
        } else {
          outb[(size_t)row * N + col] = f2b(v > 0.f ? v : 0.f);
        }
      }
    }
  }
}

// ---------- flash attention: Q,K,V bf16 [BH, S, 64] -> concat bf16 [B*S, 1024] ----------
// grid (S/64, B*H); 4 waves, wave w owns q rows [q0+16w, q0+16w+16); KVBLK=64
__global__ __launch_bounds__(256) void attn_kernel(const unsigned short* __restrict__ Q,
                                                   const unsigned short* __restrict__ K,
                                                   const unsigned short* __restrict__ V,
                                                   unsigned short* __restrict__ out) {
  const int bh = blockIdx.y;
  const int q0 = blockIdx.x * 64;
  const int tid = threadIdx.x, wid = tid >> 6, lane = tid & 63;
  const int g = lane >> 4, r15 = lane & 15;
  __shared__ __align__(16) unsigned short sK[64 * 72];   // [key][d], stride 72 (144B, 16B-aligned)
  __shared__ __align__(16) unsigned short sV[64 * 72];   // [d][key] transposed
  __shared__ __align__(16) unsigned short sP[4][16 * 72];  // per-wave P [q][key]
  const size_t base = (size_t)bh * (2048 * 64);

  const int qrow = q0 + wid * 16 + r15;
  bf16x8 qf[2];
  qf[0] = *(const bf16x8_a*)(Q + base + (size_t)qrow * 64 + g * 8);
  qf[1] = *(const bf16x8_a*)(Q + base + (size_t)qrow * 64 + 32 + g * 8);

  f32x4 o[4] = {};
  float mrow[4], lrow[4];
#pragma unroll
  for (int r = 0; r < 4; ++r) { mrow[r] = -1e30f; lrow[r] = 0.f; }

  for (int kt0 = 0; kt0 < 2048; kt0 += 64) {
// stage K tile [64][64]
#pragma unroll
    for (int j = 0; j < 2; ++j) {
      int c = tid + j * 256;
      int krow = c >> 3, kp = c & 7;
      *(u32x4_a*)&sK[krow * 72 + kp * 8] =
          *(const u32x4_a*)(K + base + (size_t)(kt0 + krow) * 64 + kp * 8);
    }
// stage V transposed: sV[d][key]
#pragma unroll
    for (int j = 0; j < 4; ++j) {
      int idx = tid + j * 256;
      int key = idx >> 4, d4 = (idx & 15) * 4;
      u16x4_a vv = *(const u16x4_a*)(V + base + (size_t)(kt0 + key) * 64 + d4);
      sV[(d4 + 0) * 72 + key] = vv[0];
      sV[(d4 + 1) * 72 + key] = vv[1];
      sV[(d4 + 2) * 72 + key] = vv[2];
      sV[(d4 + 3) * 72 + key] = vv[3];
    }
    __syncthreads();

    // scores: 16q x 64k  (A=Q rows, B=K^T)
    f32x4 sc[4] = {};
#pragma unroll
    for (int kt = 0; kt < 4; ++kt) {
      bf16x8 kf0 = *(const bf16x8_a*)&sK[(kt * 16 + r15) * 72 + g * 8];
      bf16x8 kf1 = *(const bf16x8_a*)&sK[(kt * 16 + r15) * 72 + 32 + g * 8];
      sc[kt] = __builtin_amdgcn_mfma_f32_16x16x32_bf16(qf[0], kf0, sc[kt], 0, 0, 0);
      sc[kt] = __builtin_amdgcn_mfma_f32_16x16x32_bf16(qf[1], kf1, sc[kt], 0, 0, 0);
    }

// online softmax; row = g*4+r lives in the 16 lanes of group g
#pragma unroll
    for (int r = 0; r < 4; ++r) {
      float mx = fmaxf(fmaxf(sc[0][r], sc[1][r]), fmaxf(sc[2][r], sc[3][r]));
#pragma unroll
      for (int msk = 1; msk < 16; msk <<= 1) mx = fmaxf(mx, __shfl_xor(mx, msk));
      float nm = fmaxf(mrow[r], mx);
      float fac = __expf(mrow[r] - nm);
      mrow[r] = nm;
      float ls = 0.f;
#pragma unroll
      for (int kt = 0; kt < 4; ++kt) {
        float p = __expf(sc[kt][r] - nm);
        ls += p;
        sP[wid][(g * 4 + r) * 72 + kt * 16 + r15] = f2b(p);
      }
#pragma unroll
      for (int msk = 1; msk < 16; msk <<= 1) ls += __shfl_xor(ls, msk);
      lrow[r] = lrow[r] * fac + ls;
#pragma unroll
      for (int dt = 0; dt < 4; ++dt) o[dt][r] *= fac;
    }

    // PV: A=P [16q][64key], B=V [64key][64d] via sV transposed
    bf16x8 pf0 = *(const bf16x8_a*)&sP[wid][r15 * 72 + g * 8];
    bf16x8 pf1 = *(const bf16x8_a*)&sP[wid][r15 * 72 + 32 + g * 8];
#pragma unroll
    for (int dt = 0; dt < 4; ++dt) {
      bf16x8 vf0 = *(const bf16x8_a*)&sV[(dt * 16 + r15) * 72 + g * 8];
      bf16x8 vf1 = *(const bf16x8_a*)&sV[(dt * 16 + r15) * 72 + 32 + g * 8];
      o[dt] = __builtin_amdgcn_mfma_f32_16x16x32_bf16(pf0, vf0, o[dt], 0, 0, 0);
      o[dt] = __builtin_amdgcn_mfma_f32_16x16x32_bf16(pf1, vf1, o[dt], 0, 0, 0);
    }
    __syncthreads();
  }

  // epilogue: out[b][s][h*64+d]
  const int b = bh >> 4, h = bh & 15;
#pragma unroll
  for (int r = 0; r < 4; ++r) {
    float inv = 1.f / lrow[r];
    int s = q0 + wid * 16 + g * 4 + r;
    size_t rowoff = ((size_t)(b * 2048 + s)) * 1024 + h * 64;
#pragma unroll
    for (int dt = 0; dt < 4; ++dt) out[rowoff + dt * 16 + r15] = f2b(o[dt][r] * inv);
  }
}

// ---------- LayerNorm over 1024 cols; optional f32 and bf16 outputs ----------
__global__ __launch_bounds__(256) void ln_kernel(const float* __restrict__ in,
                                                 const float* __restrict__ gamma,
                                                 const float* __restrict__ beta,
                                                 float* __restrict__ outf,
                                                 unsigned short* __restrict__ outb) {
  const int row = blockIdx.x, tid = threadIdx.x;
  float4 v = ((const float4*)(in + (size_t)row * 1024))[tid];
  float s = v.x + v.y + v.z + v.w;
  float ss = v.x * v.x + v.y * v.y + v.z * v.z + v.w * v.w;
#pragma unroll
  for (int off = 32; off > 0; off >>= 1) {
    s += __shfl_down(s, off);
    ss += __shfl_down(ss, off);
  }
  __shared__ float red[8];
  const int wid = tid >> 6;
  if ((tid & 63) == 0) { red[wid] = s; red[4 + wid] = ss; }
  __syncthreads();
  float S = red[0] + red[1] + red[2] + red[3];
  float SS = red[4] + red[5] + red[6] + red[7];
  const float mean = S * (1.f / 1024.f);
  const float var = SS * (1.f / 1024.f) - mean * mean;
  const float inv = 1.f / sqrtf(var + 1e-10f);
  float4 gg = ((const float4*)gamma)[tid];
  float4 bb = ((const float4*)beta)[tid];
  float4 o;
  o.x = (v.x - mean) * inv * gg.x + bb.x;
  o.y = (v.y - mean) * inv * gg.y + bb.y;
  o.z = (v.z - mean) * inv * gg.z + bb.z;
  o.w = (v.w - mean) * inv * gg.w + bb.w;
  if (outf) ((float4*)(outf + (size_t)row * 1024))[tid] = o;
  if (outb) {
    u16x4_a t = {f2b(o.x), f2b(o.y), f2b(o.z), f2b(o.w)};
    *(u16x4_a*)(outb + (size_t)row * 1024 + tid * 4) = t;
  }
}

// ---------- launch ----------
extern "C" void kernel_launch(void* const* d_in, const int* in_sizes, int n_in,
                              void* d_out, int out_size, void* d_ws, size_t ws_size,
                              hipStream_t stream) {
  const float* x      = (const float*)d_in[0];
  const float* wq     = (const float*)d_in[1];
  const float* bq     = (const float*)d_in[2];
  const float* wk     = (const float*)d_in[3];
  const float* bk     = (const float*)d_in[4];
  const float* wv     = (const float*)d_in[5];
  const float* bv     = (const float*)d_in[6];
  const float* w_proj = (const float*)d_in[7];
  const float* b_proj = (const float*)d_in[8];
  const float* gamma1 = (const float*)d_in[9];
  const float* beta1  = (const float*)d_in[10];
  const float* w1     = (const float*)d_in[11];
  const float* b1     = (const float*)d_in[12];
  const float* w2     = (const float*)d_in[13];
  const float* b2     = (const float*)d_in[14];
  const float* gamma2 = (const float*)d_in[15];
  const float* beta2  = (const float*)d_in[16];

  char* p = (char*)d_ws;
  auto alloc = [&](size_t bytes) {
    char* r = p;
    p += (bytes + 255) & ~(size_t)255;
    return r;
  };
  unsigned short* xb      = (unsigned short*)alloc(4096ull * 1024 * 2);  // reused as concat
  unsigned short* Wqkv_t  = (unsigned short*)alloc(3072ull * 1024 * 2);
  unsigned short* Wproj_t = (unsigned short*)alloc(1024ull * 1024 * 2);
  unsigned short* W1t     = (unsigned short*)alloc(4096ull * 1024 * 2);
  unsigned short* W2t     = (unsigned short*)alloc(1024ull * 4096 * 2);
  float*          biasq   = (float*)alloc(3072 * 4);
  unsigned short* Qb      = (unsigned short*)alloc(4096ull * 1024 * 2);
  unsigned short* Kb      = (unsigned short*)alloc(4096ull * 1024 * 2);
  unsigned short* Vb      = (unsigned short*)alloc(4096ull * 1024 * 2);
  float*          resid1  = (float*)alloc(4096ull * 1024 * 4);  // reused as resid2
  float*          out1f   = (float*)alloc(4096ull * 1024 * 4);
  unsigned short* out1b   = (unsigned short*)alloc(4096ull * 1024 * 2);
  unsigned short* ffn_h   = (unsigned short*)alloc(4096ull * 4096 * 2);
  unsigned short* concat  = xb;
  float*          resid2  = resid1;

  cvt_kernel<<<4096, 256, 0, stream>>>(x, xb, 4096 * 1024 / 4);
  transpose_cvt<<<dim3(2, 32, 16), 256, 0, stream>>>(wq, Wqkv_t, 1024, 64, 0.125f);
  transpose_cvt<<<dim3(2, 32, 16), 256, 0, stream>>>(wk, Wqkv_t + 1024 * 1024, 1024, 64, 1.f);
  transpose_cvt<<<dim3(2, 32, 16), 256, 0, stream>>>(wv, Wqkv_t + 2048 * 1024, 1024, 64, 1.f);
  transpose_cvt<<<dim3(32, 32, 1), 256, 0, stream>>>(w_proj, Wproj_t, 1024, 1024, 1.f);
  transpose_cvt<<<dim3(128, 32, 1), 256, 0, stream>>>(w1, W1t, 1024, 4096, 1.f);
  transpose_cvt<<<dim3(32, 128, 1), 256, 0, stream>>>(w2, W2t, 4096, 1024, 1.f);
  build_bias_qkv<<<12, 256, 0, stream>>>(bq, bk, bv, biasq);

  gemm_bt_kernel<0><<<dim3(24, 32), 256, 0, stream>>>(xb, Wqkv_t, 4096, 3072, 1024, biasq,
                                                      nullptr, nullptr, nullptr, Qb, Kb, Vb);
  attn_kernel<<<dim3(32, 32), 256, 0, stream>>>(Qb, Kb, Vb, concat);
  gemm_bt_kernel<1><<<dim3(8, 32), 256, 0, stream>>>(concat, Wproj_t, 4096, 1024, 1024, b_proj,
                                                     x, resid1, nullptr, nullptr, nullptr, nullptr);
  ln_kernel<<<4096, 256, 0, stream>>>(resid1, gamma1, beta1, out1f, out1b);
  gemm_bt_kernel<2><<<dim3(32, 32), 256, 0, stream>>>(out1b, W1t, 4096, 4096, 1024, b1, nullptr,
                                                      nullptr, ffn_h, nullptr, nullptr, nullptr);
  gemm_bt_kernel<1><<<dim3(8, 32), 256, 0, stream>>>(ffn_h, W2t, 4096, 1024, 4096, b2, out1f,
                                                     resid2, nullptr, nullptr, nullptr, nullptr);
  ln_kernel<<<4096, 256, 0, stream>>>(resid2, gamma2, beta2, (float*)d_out, nullptr);
}